// Round 1
// baseline (659.030 us; speedup 1.0000x reference)
//
#include <hip/hip_runtime.h>
#include <math.h>

#define NN 50000
#define NE 800000
#define EA (NE + NN)
#define NG 8
#define H 64
#define HD 128

static __device__ __forceinline__ void atomicMaxF(float* addr, float val) {
    if (val >= 0.f) atomicMax((int*)addr, __float_as_int(val));
    else            atomicMin((unsigned int*)addr, __float_as_uint(val));
}

// Layer-1 node prep: h = x@W1 (K=3), es/ed logits, init agg/max/denom.
__global__ void k_node1(const float* __restrict__ x, const float* __restrict__ W,
                        const float* __restrict__ asrc, const float* __restrict__ adst,
                        float* __restrict__ h, float* __restrict__ agg,
                        float* __restrict__ es, float* __restrict__ ed,
                        float* __restrict__ mx, float* __restrict__ dn) {
    int tid = blockIdx.x * blockDim.x + threadIdx.x;
    int node = tid >> 6, lane = tid & 63;
    if (node >= NN) return;
    float x0 = x[node*3+0], x1 = x[node*3+1], x2 = x[node*3+2];
    float hv = x0*W[lane] + x1*W[64+lane] + x2*W[128+lane];
    h[node*64+lane] = hv;
    agg[node*64+lane] = 0.f;
    float s = hv * asrc[lane], d = hv * adst[lane];
    #pragma unroll
    for (int o = 32; o > 0; o >>= 1) { s += __shfl_xor(s, o); d += __shfl_xor(d, o); }
    if (lane == 0) { es[node] = s; ed[node] = d; mx[node] = -1e30f; dn[node] = 0.f; }
}

// Layer-2 node prep: h = feat@W2 (K=64) via shfl broadcast; zeroes feat (becomes agg).
__global__ void k_node2(float* __restrict__ feat, const float* __restrict__ W,
                        const float* __restrict__ asrc, const float* __restrict__ adst,
                        float* __restrict__ h, float* __restrict__ es, float* __restrict__ ed,
                        float* __restrict__ mx, float* __restrict__ dn) {
    int tid = blockIdx.x * blockDim.x + threadIdx.x;
    int node = tid >> 6, lane = tid & 63;
    if (node >= NN) return;
    float v = feat[node*64+lane];
    float hv = 0.f;
    #pragma unroll
    for (int k = 0; k < 64; ++k) hv += __shfl(v, k) * W[k*64+lane];
    h[node*64+lane] = hv;
    feat[node*64+lane] = 0.f;
    float s = hv * asrc[lane], d = hv * adst[lane];
    #pragma unroll
    for (int o = 32; o > 0; o >>= 1) { s += __shfl_xor(s, o); d += __shfl_xor(d, o); }
    if (lane == 0) { es[node] = s; ed[node] = d; mx[node] = -1e30f; dn[node] = 0.f; }
}

__global__ void k_edge_max(const int* __restrict__ src, const int* __restrict__ dst,
                           const float* __restrict__ es, const float* __restrict__ ed,
                           float* __restrict__ mx) {
    int e = blockIdx.x * blockDim.x + threadIdx.x;
    if (e >= EA) return;
    int s, d;
    if (e < NE) { s = src[e]; d = dst[e]; } else { s = d = e - NE; }
    float ev = es[s] + ed[d];
    ev = ev > 0.f ? ev : 0.2f * ev;
    atomicMaxF(&mx[d], ev);
}

__global__ void k_edge_sum(const int* __restrict__ src, const int* __restrict__ dst,
                           const float* __restrict__ es, const float* __restrict__ ed,
                           const float* __restrict__ mx, float* __restrict__ dn) {
    int e = blockIdx.x * blockDim.x + threadIdx.x;
    if (e >= EA) return;
    int s, d;
    if (e < NE) { s = src[e]; d = dst[e]; } else { s = d = e - NE; }
    float ev = es[s] + ed[d];
    ev = ev > 0.f ? ev : 0.2f * ev;
    atomicAdd(&dn[d], __expf(ev - mx[d]));
}

// One wave per edge: lane = channel.
__global__ void k_edge_agg(const int* __restrict__ src, const int* __restrict__ dst,
                           const float* __restrict__ es, const float* __restrict__ ed,
                           const float* __restrict__ mx, const float* __restrict__ dn,
                           const float* __restrict__ h, float* __restrict__ agg) {
    int tid = blockIdx.x * blockDim.x + threadIdx.x;
    int e = tid >> 6, lane = tid & 63;
    if (e >= EA) return;
    int s, d;
    if (e < NE) { s = src[e]; d = dst[e]; } else { s = d = e - NE; }
    float ev = es[s] + ed[d];
    ev = ev > 0.f ? ev : 0.2f * ev;
    float alpha = __expf(ev - mx[d]) / dn[d];
    atomicAdd(&agg[d*64 + lane], h[s*64 + lane] * alpha);
}

__global__ void k_finish(float* __restrict__ agg, const float* __restrict__ b) {
    int idx = blockIdx.x * blockDim.x + threadIdx.x;
    if (idx >= NN * 64) return;
    float v = agg[idx] + b[idx & 63];
    agg[idx] = v > 0.f ? v : 0.f;
}

__global__ void k_zero(float* __restrict__ p, int n) {
    for (int i = threadIdx.x; i < n; i += blockDim.x) p[i] = 0.f;
}

__global__ void k_pool(const float* __restrict__ feat, const int* __restrict__ batch,
                       float* __restrict__ sums, float* __restrict__ cnt) {
    __shared__ float part[NG * H];
    __shared__ float pc[NG];
    for (int i = threadIdx.x; i < NG * H; i += blockDim.x) part[i] = 0.f;
    if (threadIdx.x < NG) pc[threadIdx.x] = 0.f;
    __syncthreads();
    int total = NN * H;
    for (int idx = blockIdx.x * blockDim.x + threadIdx.x; idx < total;
         idx += gridDim.x * blockDim.x) {
        int node = idx >> 6, c = idx & 63;
        int g = batch[node];
        atomicAdd(&part[g * H + c], feat[idx]);
        if (c == 0) atomicAdd(&pc[g], 1.f);
    }
    __syncthreads();
    for (int i = threadIdx.x; i < NG * H; i += blockDim.x) atomicAdd(&sums[i], part[i]);
    if (threadIdx.x < NG) atomicAdd(&cnt[threadIdx.x], pc[threadIdx.x]);
}

__global__ void k_head(const float* __restrict__ sums, const float* __restrict__ cnt,
                       const float* __restrict__ Wh1, const float* __restrict__ bh1,
                       const float* __restrict__ Wh2, const float* __restrict__ bh2,
                       float* __restrict__ out) {
    __shared__ float pooled[NG * H];
    __shared__ float hidden[NG * HD];
    int t = threadIdx.x;
    for (int i = t; i < NG * H; i += blockDim.x) {
        float c = cnt[i >> 6];
        pooled[i] = sums[i] / fmaxf(c, 1.f);
    }
    __syncthreads();
    for (int i = t; i < NG * HD; i += blockDim.x) {
        int g = i / HD, hd = i % HD;
        float acc = bh1[hd];
        for (int c = 0; c < H; ++c) acc += pooled[g * H + c] * Wh1[c * HD + hd];
        hidden[i] = fmaxf(acc, 0.f);
    }
    __syncthreads();
    if (t < NG) {
        float acc = bh2[0];
        for (int hd = 0; hd < HD; ++hd) acc += hidden[t * HD + hd] * Wh2[hd];
        out[t] = acc;
    }
}

extern "C" void kernel_launch(void* const* d_in, const int* in_sizes, int n_in,
                              void* d_out, int out_size, void* d_ws, size_t ws_size,
                              hipStream_t stream) {
    const float* x    = (const float*)d_in[0];
    const int*   ei   = (const int*)d_in[1];
    const int*   batch= (const int*)d_in[2];
    const float* W1   = (const float*)d_in[3];
    const float* as1  = (const float*)d_in[4];
    const float* ad1  = (const float*)d_in[5];
    const float* b1   = (const float*)d_in[6];
    const float* W2   = (const float*)d_in[7];
    const float* as2  = (const float*)d_in[8];
    const float* ad2  = (const float*)d_in[9];
    const float* b2   = (const float*)d_in[10];
    const float* Wh1  = (const float*)d_in[11];
    const float* bh1  = (const float*)d_in[12];
    const float* Wh2  = (const float*)d_in[13];
    const float* bh2  = (const float*)d_in[14];
    const int* src = ei;
    const int* dst = ei + NE;

    float* ws   = (float*)d_ws;
    float* h    = ws;                  // NN*64
    float* feat = ws + (size_t)NN*64;  // NN*64 (features <-> agg, reused)
    float* es   = ws + (size_t)2*NN*64;
    float* ed   = es + NN;
    float* mx   = ed + NN;
    float* dn   = mx + NN;
    float* sums = dn + NN;             // NG*64
    float* cnt  = sums + NG*H;         // NG

    dim3 blk(256);
    int nodeBlocks = (NN * 64) / 256;        // 12500
    int edgeBlocks = (EA + 255) / 256;       // 3321
    int aggBlocks  = (EA * 64) / 256;        // 212500

    // ---- layer 1 ----
    k_node1<<<nodeBlocks, blk, 0, stream>>>(x, W1, as1, ad1, h, feat, es, ed, mx, dn);
    k_edge_max<<<edgeBlocks, blk, 0, stream>>>(src, dst, es, ed, mx);
    k_edge_sum<<<edgeBlocks, blk, 0, stream>>>(src, dst, es, ed, mx, dn);
    k_edge_agg<<<aggBlocks, blk, 0, stream>>>(src, dst, es, ed, mx, dn, h, feat);
    k_finish<<<nodeBlocks, blk, 0, stream>>>(feat, b1);

    // ---- layer 2 ----
    k_node2<<<nodeBlocks, blk, 0, stream>>>(feat, W2, as2, ad2, h, es, ed, mx, dn);
    k_edge_max<<<edgeBlocks, blk, 0, stream>>>(src, dst, es, ed, mx);
    k_edge_sum<<<edgeBlocks, blk, 0, stream>>>(src, dst, es, ed, mx, dn);
    k_edge_agg<<<aggBlocks, blk, 0, stream>>>(src, dst, es, ed, mx, dn, h, feat);
    k_finish<<<nodeBlocks, blk, 0, stream>>>(feat, b2);

    // ---- pool + head ----
    k_zero<<<1, 256, 0, stream>>>(sums, NG * H + NG);
    k_pool<<<512, blk, 0, stream>>>(feat, batch, sums, cnt);
    k_head<<<1, 256, 0, stream>>>(sums, cnt, Wh1, bh1, Wh2, bh2, (float*)d_out);
}

// Round 2
// 488.503 us; speedup vs baseline: 1.3491x; 1.3491x over previous
//
#include <hip/hip_runtime.h>
#include <math.h>

#define NN 50000
#define NE 800000
#define EA (NE + NN)
#define NG 8
#define H 64
#define HD 128

// ---------------- CSR build (once per call, reused by both layers) ----------------

__global__ void k_deg_init(int* __restrict__ deg) {
    int i = blockIdx.x * blockDim.x + threadIdx.x;
    if (i < NN) deg[i] = 1;              // self-loop
}

__global__ void k_count(const int* __restrict__ dst, int* __restrict__ deg) {
    int e = blockIdx.x * blockDim.x + threadIdx.x;
    if (e < NE) atomicAdd(&deg[dst[e]], 1);
}

// Single-block exclusive scan over NN degrees -> row_off, cur.
__global__ void k_scan(const int* __restrict__ deg, int* __restrict__ row_off,
                       int* __restrict__ cur) {
    __shared__ int ssum[1024];
    int t = threadIdx.x;
    const int C = (NN + 1023) / 1024;    // 49
    int b = t * C, e = b + C; if (e > NN) e = NN; if (b > NN) b = NN;
    int s = 0;
    for (int i = b; i < e; ++i) s += deg[i];
    ssum[t] = s;
    __syncthreads();
    for (int off = 1; off < 1024; off <<= 1) {
        int v = (t >= off) ? ssum[t - off] : 0;
        __syncthreads();
        ssum[t] += v;
        __syncthreads();
    }
    int run = (t == 0) ? 0 : ssum[t - 1];
    for (int i = b; i < e; ++i) { row_off[i] = run; cur[i] = run; run += deg[i]; }
    if (t == 1023) row_off[NN] = EA;
}

__global__ void k_scatter(const int* __restrict__ src, const int* __restrict__ dst,
                          int* __restrict__ cur, int* __restrict__ csr) {
    int e = blockIdx.x * blockDim.x + threadIdx.x;
    if (e >= EA) return;
    int s, d;
    if (e < NE) { s = src[e]; d = dst[e]; } else { s = d = e - NE; }
    int p = atomicAdd(&cur[d], 1);
    csr[p] = s;
}

// ---------------- node prep ----------------

__global__ void k_node1(const float* __restrict__ x, const float* __restrict__ W,
                        const float* __restrict__ asrc, const float* __restrict__ adst,
                        float* __restrict__ h, float* __restrict__ es, float* __restrict__ ed) {
    int tid = blockIdx.x * blockDim.x + threadIdx.x;
    int node = tid >> 6, lane = tid & 63;
    if (node >= NN) return;
    float x0 = x[node*3+0], x1 = x[node*3+1], x2 = x[node*3+2];
    float hv = x0*W[lane] + x1*W[64+lane] + x2*W[128+lane];
    h[node*64+lane] = hv;
    float s = hv * asrc[lane], d = hv * adst[lane];
    #pragma unroll
    for (int o = 32; o > 0; o >>= 1) { s += __shfl_xor(s, o); d += __shfl_xor(d, o); }
    if (lane == 0) { es[node] = s; ed[node] = d; }
}

__global__ void k_node2(const float* __restrict__ feat, const float* __restrict__ W,
                        const float* __restrict__ asrc, const float* __restrict__ adst,
                        float* __restrict__ h, float* __restrict__ es, float* __restrict__ ed) {
    int tid = blockIdx.x * blockDim.x + threadIdx.x;
    int node = tid >> 6, lane = tid & 63;
    if (node >= NN) return;
    float v = feat[node*64+lane];
    float hv = 0.f;
    #pragma unroll
    for (int k = 0; k < 64; ++k) hv += __shfl(v, k) * W[k*64+lane];
    h[node*64+lane] = hv;
    float s = hv * asrc[lane], d = hv * adst[lane];
    #pragma unroll
    for (int o = 32; o > 0; o >>= 1) { s += __shfl_xor(s, o); d += __shfl_xor(d, o); }
    if (lane == 0) { es[node] = s; ed[node] = d; }
}

// ---------------- fused softmax + aggregation: one wave per destination node ----------------

__global__ void k_gather(const int* __restrict__ row_off, const int* __restrict__ csr,
                         const float* __restrict__ es, const float* __restrict__ ed,
                         const float* __restrict__ h, const float* __restrict__ b,
                         float* __restrict__ out) {
    int tid = blockIdx.x * blockDim.x + threadIdx.x;
    int node = tid >> 6, lane = tid & 63;
    if (node >= NN) return;
    int beg = row_off[node], end = row_off[node + 1];
    float edn = ed[node];

    // phase A: max over incoming edges (lane = edge)
    float m = -1e30f;
    for (int i = beg + lane; i < end; i += 64) {
        float ev = es[csr[i]] + edn;
        ev = ev > 0.f ? ev : 0.2f * ev;
        m = fmaxf(m, ev);
    }
    #pragma unroll
    for (int o = 32; o > 0; o >>= 1) m = fmaxf(m, __shfl_xor(m, o));

    // phase B: sum of exp (lane = edge)
    float sum = 0.f;
    for (int i = beg + lane; i < end; i += 64) {
        float ev = es[csr[i]] + edn;
        ev = ev > 0.f ? ev : 0.2f * ev;
        sum += __expf(ev - m);
    }
    #pragma unroll
    for (int o = 32; o > 0; o >>= 1) sum += __shfl_xor(sum, o);
    float inv = 1.0f / sum;

    // phase C: weighted accumulation (lane = channel, serial over edges)
    float acc = 0.f;
    for (int i = beg; i < end; ++i) {
        int s = csr[i];
        float ev = es[s] + edn;
        ev = ev > 0.f ? ev : 0.2f * ev;
        float alpha = __expf(ev - m) * inv;
        acc += h[s*64 + lane] * alpha;
    }
    out[node*64 + lane] = fmaxf(acc + b[lane], 0.f);
}

// ---------------- pool + head ----------------

__global__ void k_zero(float* __restrict__ p, int n) {
    for (int i = threadIdx.x; i < n; i += blockDim.x) p[i] = 0.f;
}

__global__ void k_pool(const float* __restrict__ feat, const int* __restrict__ batch,
                       float* __restrict__ sums, float* __restrict__ cnt) {
    __shared__ float part[NG * H];
    __shared__ float pc[NG];
    for (int i = threadIdx.x; i < NG * H; i += blockDim.x) part[i] = 0.f;
    if (threadIdx.x < NG) pc[threadIdx.x] = 0.f;
    __syncthreads();
    int total = NN * H;
    for (int idx = blockIdx.x * blockDim.x + threadIdx.x; idx < total;
         idx += gridDim.x * blockDim.x) {
        int node = idx >> 6, c = idx & 63;
        int g = batch[node];
        atomicAdd(&part[g * H + c], feat[idx]);
        if (c == 0) atomicAdd(&pc[g], 1.f);
    }
    __syncthreads();
    for (int i = threadIdx.x; i < NG * H; i += blockDim.x) atomicAdd(&sums[i], part[i]);
    if (threadIdx.x < NG) atomicAdd(&cnt[threadIdx.x], pc[threadIdx.x]);
}

__global__ void k_head(const float* __restrict__ sums, const float* __restrict__ cnt,
                       const float* __restrict__ Wh1, const float* __restrict__ bh1,
                       const float* __restrict__ Wh2, const float* __restrict__ bh2,
                       float* __restrict__ out) {
    __shared__ float pooled[NG * H];
    __shared__ float hidden[NG * HD];
    int t = threadIdx.x;
    for (int i = t; i < NG * H; i += blockDim.x) {
        float c = cnt[i >> 6];
        pooled[i] = sums[i] / fmaxf(c, 1.f);
    }
    __syncthreads();
    for (int i = t; i < NG * HD; i += blockDim.x) {
        int g = i / HD, hd = i % HD;
        float acc = bh1[hd];
        for (int c = 0; c < H; ++c) acc += pooled[g * H + c] * Wh1[c * HD + hd];
        hidden[i] = fmaxf(acc, 0.f);
    }
    __syncthreads();
    if (t < NG) {
        float acc = bh2[0];
        for (int hd = 0; hd < HD; ++hd) acc += hidden[t * HD + hd] * Wh2[hd];
        out[t] = acc;
    }
}

extern "C" void kernel_launch(void* const* d_in, const int* in_sizes, int n_in,
                              void* d_out, int out_size, void* d_ws, size_t ws_size,
                              hipStream_t stream) {
    const float* x    = (const float*)d_in[0];
    const int*   ei   = (const int*)d_in[1];
    const int*   batch= (const int*)d_in[2];
    const float* W1   = (const float*)d_in[3];
    const float* as1  = (const float*)d_in[4];
    const float* ad1  = (const float*)d_in[5];
    const float* b1   = (const float*)d_in[6];
    const float* W2   = (const float*)d_in[7];
    const float* as2  = (const float*)d_in[8];
    const float* ad2  = (const float*)d_in[9];
    const float* b2   = (const float*)d_in[10];
    const float* Wh1  = (const float*)d_in[11];
    const float* bh1  = (const float*)d_in[12];
    const float* Wh2  = (const float*)d_in[13];
    const float* bh2  = (const float*)d_in[14];
    const int* src = ei;
    const int* dst = ei + NE;

    float* ws   = (float*)d_ws;
    float* h    = ws;                         // NN*64
    float* feat = h + (size_t)NN*64;          // NN*64
    float* es   = feat + (size_t)NN*64;       // NN
    float* ed   = es + NN;                    // NN
    float* sums = ed + NN;                    // NG*H
    float* cnt  = sums + NG*H;                // NG
    int*   row_off = (int*)(cnt + NG);        // NN+1
    int*   cur     = row_off + NN + 1;        // NN (also deg)
    int*   csr     = cur + NN;                // EA

    dim3 blk(256);
    int nodeBlocks  = (NN * 64) / 256;        // 12500
    int nBlocks     = (NN + 255) / 256;       // 196
    int eBlocks     = (NE + 255) / 256;       // 3125
    int eaBlocks    = (EA + 255) / 256;       // 3321

    // ---- CSR build (deg stored in `cur`, then overwritten with cursors by k_scan) ----
    k_deg_init<<<nBlocks, blk, 0, stream>>>(cur);
    k_count<<<eBlocks, blk, 0, stream>>>(dst, cur);
    k_scan<<<1, 1024, 0, stream>>>(cur, row_off, cur);
    k_scatter<<<eaBlocks, blk, 0, stream>>>(src, dst, cur, csr);

    // ---- layer 1 ----
    k_node1<<<nodeBlocks, blk, 0, stream>>>(x, W1, as1, ad1, h, es, ed);
    k_gather<<<nodeBlocks, blk, 0, stream>>>(row_off, csr, es, ed, h, b1, feat);

    // ---- layer 2 ----
    k_node2<<<nodeBlocks, blk, 0, stream>>>(feat, W2, as2, ad2, h, es, ed);
    k_gather<<<nodeBlocks, blk, 0, stream>>>(row_off, csr, es, ed, h, b2, feat);

    // ---- pool + head ----
    k_zero<<<1, 256, 0, stream>>>(sums, NG * H + NG);
    k_pool<<<512, blk, 0, stream>>>(feat, batch, sums, cnt);
    k_head<<<1, 256, 0, stream>>>(sums, cnt, Wh1, bh1, Wh2, bh2, (float*)d_out);
}

// Round 3
// 317.473 us; speedup vs baseline: 2.0759x; 1.5387x over previous
//
#include <hip/hip_runtime.h>
#include <math.h>

#define NN 50000
#define NE 800000
#define EA (NE + NN)
#define NG 8
#define H 64
#define HD 128

// ---------------- CSR build (scan-free) ----------------

__global__ void k_deg_init(int* __restrict__ deg, int* __restrict__ counter) {
    int i = blockIdx.x * blockDim.x + threadIdx.x;
    if (i < NN) deg[i] = 1;              // self-loop
    if (i == 0) *counter = 0;
}

__global__ void k_count(const int* __restrict__ dst, int* __restrict__ deg) {
    int e = blockIdx.x * blockDim.x + threadIdx.x;
    if (e < NE) atomicAdd(&deg[dst[e]], 1);
}

// Wave-level prefix over degrees + one global atomic per wave -> row offsets.
// Rows are NOT in node order (allocation order is arbitrary) — that's fine,
// gather only needs [row_off[n], row_off[n]+deg[n]) contiguous.
__global__ void k_alloc(const int* __restrict__ deg, int* __restrict__ row_off,
                        int* __restrict__ cur, int* __restrict__ counter) {
    int i = blockIdx.x * blockDim.x + threadIdx.x;
    int lane = threadIdx.x & 63;
    int d = (i < NN) ? deg[i] : 0;
    int s = d;
    #pragma unroll
    for (int o = 1; o < 64; o <<= 1) {
        int v = __shfl_up(s, o);
        if (lane >= o) s += v;
    }
    int total = __shfl(s, 63);
    int base = 0;
    if (lane == 63) base = atomicAdd(counter, total);
    base = __shfl(base, 63);
    if (i < NN) {
        int off = base + s - d;   // exclusive within-wave + wave base
        row_off[i] = off;
        cur[i] = off;
    }
}

__global__ void k_scatter(const int* __restrict__ src, const int* __restrict__ dst,
                          int* __restrict__ cur, int* __restrict__ csr) {
    int e = blockIdx.x * blockDim.x + threadIdx.x;
    if (e >= EA) return;
    int s, d;
    if (e < NE) { s = src[e]; d = dst[e]; } else { s = d = e - NE; }
    int p = atomicAdd(&cur[d], 1);
    csr[p] = s;
}

// ---------------- node prep ----------------

__global__ void k_node1(const float* __restrict__ x, const float* __restrict__ W,
                        const float* __restrict__ asrc, const float* __restrict__ adst,
                        float* __restrict__ h, float* __restrict__ es, float* __restrict__ ed) {
    int tid = blockIdx.x * blockDim.x + threadIdx.x;
    int node = tid >> 6, lane = tid & 63;
    if (node >= NN) return;
    float x0 = x[node*3+0], x1 = x[node*3+1], x2 = x[node*3+2];
    float hv = x0*W[lane] + x1*W[64+lane] + x2*W[128+lane];
    h[node*64+lane] = hv;
    float s = hv * asrc[lane], d = hv * adst[lane];
    #pragma unroll
    for (int o = 32; o > 0; o >>= 1) { s += __shfl_xor(s, o); d += __shfl_xor(d, o); }
    if (lane == 0) { es[node] = s; ed[node] = d; }
}

__global__ void k_node2(const float* __restrict__ feat, const float* __restrict__ W,
                        const float* __restrict__ asrc, const float* __restrict__ adst,
                        float* __restrict__ h, float* __restrict__ es, float* __restrict__ ed) {
    int tid = blockIdx.x * blockDim.x + threadIdx.x;
    int node = tid >> 6, lane = tid & 63;
    if (node >= NN) return;
    float v = feat[node*64+lane];
    float hv = 0.f;
    #pragma unroll
    for (int k = 0; k < 64; ++k) hv += __shfl(v, k) * W[k*64+lane];
    h[node*64+lane] = hv;
    float s = hv * asrc[lane], d = hv * adst[lane];
    #pragma unroll
    for (int o = 32; o > 0; o >>= 1) { s += __shfl_xor(s, o); d += __shfl_xor(d, o); }
    if (lane == 0) { es[node] = s; ed[node] = d; }
}

// ---------------- fused softmax + aggregation: one wave per destination node ----------------

__global__ void k_gather(const int* __restrict__ row_off, const int* __restrict__ deg,
                         const int* __restrict__ csr,
                         const float* __restrict__ es, const float* __restrict__ ed,
                         const float* __restrict__ h, const float* __restrict__ b,
                         float* __restrict__ out) {
    int tid = blockIdx.x * blockDim.x + threadIdx.x;
    int node = tid >> 6, lane = tid & 63;
    if (node >= NN) return;
    int beg = row_off[node];
    int n = deg[node];
    float edn = ed[node];
    float acc = 0.f;

    if (n <= 128) {
        // register-cached fast path: each lane owns up to 2 edges
        int s0 = 0, s1 = 0;
        float ev0 = -1e30f, ev1 = -1e30f;
        if (lane < n) {
            s0 = csr[beg + lane];
            float e0 = es[s0] + edn;
            ev0 = e0 > 0.f ? e0 : 0.2f * e0;
        }
        if (64 + lane < n) {
            s1 = csr[beg + 64 + lane];
            float e1 = es[s1] + edn;
            ev1 = e1 > 0.f ? e1 : 0.2f * e1;
        }
        float m = fmaxf(ev0, ev1);
        #pragma unroll
        for (int o = 32; o > 0; o >>= 1) m = fmaxf(m, __shfl_xor(m, o));
        float p0 = (lane < n) ? __expf(ev0 - m) : 0.f;
        float p1 = (64 + lane < n) ? __expf(ev1 - m) : 0.f;
        float sum = p0 + p1;
        #pragma unroll
        for (int o = 32; o > 0; o >>= 1) sum += __shfl_xor(sum, o);
        float inv = 1.0f / sum;
        p0 *= inv; p1 *= inv;

        int k0 = n < 64 ? n : 64;
        for (int k = 0; k < k0; ++k) {
            int s = __shfl(s0, k);
            float p = __shfl(p0, k);
            acc += h[s*64 + lane] * p;
        }
        for (int k = 64; k < n; ++k) {
            int s = __shfl(s1, k - 64);
            float p = __shfl(p1, k - 64);
            acc += h[s*64 + lane] * p;
        }
    } else {
        // generic fallback (3 passes)
        int end = beg + n;
        float m = -1e30f;
        for (int i = beg + lane; i < end; i += 64) {
            float ev = es[csr[i]] + edn;
            ev = ev > 0.f ? ev : 0.2f * ev;
            m = fmaxf(m, ev);
        }
        #pragma unroll
        for (int o = 32; o > 0; o >>= 1) m = fmaxf(m, __shfl_xor(m, o));
        float sum = 0.f;
        for (int i = beg + lane; i < end; i += 64) {
            float ev = es[csr[i]] + edn;
            ev = ev > 0.f ? ev : 0.2f * ev;
            sum += __expf(ev - m);
        }
        #pragma unroll
        for (int o = 32; o > 0; o >>= 1) sum += __shfl_xor(sum, o);
        float inv = 1.0f / sum;
        for (int i = beg; i < end; ++i) {
            int s = csr[i];
            float ev = es[s] + edn;
            ev = ev > 0.f ? ev : 0.2f * ev;
            acc += h[s*64 + lane] * (__expf(ev - m) * inv);
        }
    }
    out[node*64 + lane] = fmaxf(acc + b[lane], 0.f);
}

// ---------------- pool + head ----------------

__global__ void k_zero(float* __restrict__ p, int n) {
    for (int i = threadIdx.x; i < n; i += blockDim.x) p[i] = 0.f;
}

__global__ void k_pool(const float* __restrict__ feat, const int* __restrict__ batch,
                       float* __restrict__ sums, float* __restrict__ cnt) {
    __shared__ float part[NG * H];
    __shared__ float pc[NG];
    for (int i = threadIdx.x; i < NG * H; i += blockDim.x) part[i] = 0.f;
    if (threadIdx.x < NG) pc[threadIdx.x] = 0.f;
    __syncthreads();
    int total = NN * H;
    for (int idx = blockIdx.x * blockDim.x + threadIdx.x; idx < total;
         idx += gridDim.x * blockDim.x) {
        int node = idx >> 6, c = idx & 63;
        int g = batch[node];
        atomicAdd(&part[g * H + c], feat[idx]);
        if (c == 0) atomicAdd(&pc[g], 1.f);
    }
    __syncthreads();
    for (int i = threadIdx.x; i < NG * H; i += blockDim.x) atomicAdd(&sums[i], part[i]);
    if (threadIdx.x < NG) atomicAdd(&cnt[threadIdx.x], pc[threadIdx.x]);
}

__global__ void k_head(const float* __restrict__ sums, const float* __restrict__ cnt,
                       const float* __restrict__ Wh1, const float* __restrict__ bh1,
                       const float* __restrict__ Wh2, const float* __restrict__ bh2,
                       float* __restrict__ out) {
    __shared__ float pooled[NG * H];
    __shared__ float hidden[NG * HD];
    int t = threadIdx.x;
    for (int i = t; i < NG * H; i += blockDim.x) {
        float c = cnt[i >> 6];
        pooled[i] = sums[i] / fmaxf(c, 1.f);
    }
    __syncthreads();
    for (int i = t; i < NG * HD; i += blockDim.x) {
        int g = i / HD, hd = i % HD;
        float acc = bh1[hd];
        for (int c = 0; c < H; ++c) acc += pooled[g * H + c] * Wh1[c * HD + hd];
        hidden[i] = fmaxf(acc, 0.f);
    }
    __syncthreads();
    if (t < NG) {
        float acc = bh2[0];
        for (int hd = 0; hd < HD; ++hd) acc += hidden[t * HD + hd] * Wh2[hd];
        out[t] = acc;
    }
}

extern "C" void kernel_launch(void* const* d_in, const int* in_sizes, int n_in,
                              void* d_out, int out_size, void* d_ws, size_t ws_size,
                              hipStream_t stream) {
    const float* x    = (const float*)d_in[0];
    const int*   ei   = (const int*)d_in[1];
    const int*   batch= (const int*)d_in[2];
    const float* W1   = (const float*)d_in[3];
    const float* as1  = (const float*)d_in[4];
    const float* ad1  = (const float*)d_in[5];
    const float* b1   = (const float*)d_in[6];
    const float* W2   = (const float*)d_in[7];
    const float* as2  = (const float*)d_in[8];
    const float* ad2  = (const float*)d_in[9];
    const float* b2   = (const float*)d_in[10];
    const float* Wh1  = (const float*)d_in[11];
    const float* bh1  = (const float*)d_in[12];
    const float* Wh2  = (const float*)d_in[13];
    const float* bh2  = (const float*)d_in[14];
    const int* src = ei;
    const int* dst = ei + NE;

    float* ws   = (float*)d_ws;
    float* h    = ws;                         // NN*64
    float* feat = h + (size_t)NN*64;          // NN*64
    float* es   = feat + (size_t)NN*64;       // NN
    float* ed   = es + NN;                    // NN
    float* sums = ed + NN;                    // NG*H
    float* cnt  = sums + NG*H;                // NG
    int*   deg     = (int*)(cnt + NG);        // NN
    int*   row_off = deg + NN;                // NN
    int*   cur     = row_off + NN;            // NN
    int*   counter = cur + NN;                // 1
    int*   csr     = counter + 1;             // EA

    dim3 blk(256);
    int nodeBlocks  = (NN * 64) / 256;        // 12500
    int nBlocks     = (NN + 255) / 256;       // 196
    int eBlocks     = (NE + 255) / 256;       // 3125
    int eaBlocks    = (EA + 255) / 256;       // 3321

    // ---- CSR build ----
    k_deg_init<<<nBlocks, blk, 0, stream>>>(deg, counter);
    k_count<<<eBlocks, blk, 0, stream>>>(dst, deg);
    k_alloc<<<nBlocks, blk, 0, stream>>>(deg, row_off, cur, counter);
    k_scatter<<<eaBlocks, blk, 0, stream>>>(src, dst, cur, csr);

    // ---- layer 1 ----
    k_node1<<<nodeBlocks, blk, 0, stream>>>(x, W1, as1, ad1, h, es, ed);
    k_gather<<<nodeBlocks, blk, 0, stream>>>(row_off, deg, csr, es, ed, h, b1, feat);

    // ---- layer 2 ----
    k_node2<<<nodeBlocks, blk, 0, stream>>>(feat, W2, as2, ad2, h, es, ed);
    k_gather<<<nodeBlocks, blk, 0, stream>>>(row_off, deg, csr, es, ed, h, b2, feat);

    // ---- pool + head ----
    k_zero<<<1, 256, 0, stream>>>(sums, NG * H + NG);
    k_pool<<<512, blk, 0, stream>>>(feat, batch, sums, cnt);
    k_head<<<1, 256, 0, stream>>>(sums, cnt, Wh1, bh1, Wh2, bh2, (float*)d_out);
}